// Round 1
// baseline (135.082 us; speedup 1.0000x reference)
//
#include <hip/hip_runtime.h>
#include <math.h>

// DMPNet fused kernel, MI355X.
// Closed-form DMP: y_T = a_T*y0 + h_T*0.05 + c_T*goal + (goal-y0)*(w . V_T)
// Table (11 x 8 floats) computed per-launch by a tiny setup kernel into d_ws.

// ---------------- setup kernel: build coefficient table ----------------
// tbl[tt*8 + 0] = a_T   (y0 coefficient,  (A^T)_00)
// tbl[tt*8 + 1] = c_T   (goal coefficient, 0.5625 * sum_{k<T} h_k)
// tbl[tt*8 + 2] = d_T   (constant term, h_T * z0 with z0 = 0.05)
// tbl[tt*8 + 3+i] = V_T[i] = 0.01 * sum_{s=1..T} h_{T-s} * v_s[i]
__global__ void dmp_setup_kernel(float* __restrict__ tbl) {
    __shared__ float vv[101][5];
    __shared__ float hh[101];
    __shared__ float aa[101];
    const int t = threadIdx.x;
    if (t <= 100) {
        // A^t by square-and-multiply, A = [[1, 0.01], [-0.5625, 0.85]]
        float m00 = 1.f, m01 = 0.f, m10 = 0.f, m11 = 1.f;
        float p00 = 1.f, p01 = 0.01f, p10 = -0.5625f, p11 = 0.85f;
        int e = t;
        while (e) {
            if (e & 1) {
                const float n00 = m00 * p00 + m01 * p10;
                const float n01 = m00 * p01 + m01 * p11;
                const float n10 = m10 * p00 + m11 * p10;
                const float n11 = m10 * p01 + m11 * p11;
                m00 = n00; m01 = n01; m10 = n10; m11 = n11;
            }
            const float q00 = p00 * p00 + p01 * p10;
            const float q01 = p00 * p01 + p01 * p11;
            const float q10 = p10 * p00 + p11 * p10;
            const float q11 = p10 * p01 + p11 * p11;
            p00 = q00; p01 = q01; p10 = q10; p11 = q11;
            e >>= 1;
        }
        hh[t] = m01;
        aa[t] = m00;
        if (t >= 1) {
            // canonical system value x_s = 0.99^s (sequential, matching ref)
            float xs = 1.0f;
            for (int i = 0; i < t; ++i) xs *= 0.99f;
            float psi[5];
            float sum = 0.f;
#pragma unroll
            for (int i = 0; i < 5; ++i) {
                const float ci = expf(-0.25f * (float)i);          // c_i
                const float s2 = 11.180339887498949f / ci;          // sigma2_i = 5^1.5 / c_i
                const float dxc = xs - ci;
                psi[i] = expf(-0.5f * dxc * dxc / s2);
                sum += psi[i];
            }
#pragma unroll
            for (int i = 0; i < 5; ++i) vv[t][i] = psi[i] * xs / sum;
        }
    }
    __syncthreads();
    if (t < 66) {
        const int tt = t / 6, q = t - tt * 6, T = 10 * tt;
        if (q == 0) {
            float cg = 0.f;
            for (int k = 0; k < T; ++k) cg += hh[k];
            tbl[tt * 8 + 0] = aa[T];
            tbl[tt * 8 + 1] = 0.5625f * cg;
            tbl[tt * 8 + 2] = hh[T] * 0.05f;   // z0 = dy0 * TAU = 0.05
        } else {
            const int i = q - 1;
            float V = 0.f;
            for (int s = 1; s <= T; ++s) V += hh[T - s] * vv[s][i];
            tbl[tt * 8 + 3 + i] = 0.01f * V;
        }
    }
}

// ---------------- main kernel: GEMM (W via scalar broadcast) + closed-form DMP ----
// 1024 blocks x 256 threads; block owns 64 batch rows; wave w owns k in [64w, 64w+64)
__global__ __launch_bounds__(256) void dmp_main_kernel(
    const float* __restrict__ x,      // [65536, 256]
    const float* __restrict__ state,  // [65536, 7]
    const float* __restrict__ W,      // [256, 42]
    const float* __restrict__ bias,   // [42]
    const float* __restrict__ tbl,    // [11, 8]
    float* __restrict__ out)          // [65536, 11, 7]
{
    __shared__ float part[42 * 256];  // [c][wave*64 + lane], 43008 B

    const int tid = threadIdx.x;
    const int wave = __builtin_amdgcn_readfirstlane(tid >> 6);  // uniform -> s_load for W
    const int lane = tid & 63;
    const int blk = blockIdx.x;
    const size_t row = (size_t)blk * 64 + lane;

    float acc[42];
#pragma unroll
    for (int c = 0; c < 42; ++c) acc[c] = 0.f;

    const float* xr = x + row * 256 + (size_t)(wave * 64);
    const float* Wq = W + (size_t)(wave * 64) * 42;

    for (int kk = 0; kk < 64; kk += 4) {
        const float4 xv = *reinterpret_cast<const float4*>(xr + kk);
#pragma unroll
        for (int i = 0; i < 4; ++i) {
            const float xs = (i == 0) ? xv.x : (i == 1) ? xv.y : (i == 2) ? xv.z : xv.w;
            const float* Wr = Wq + (kk + i) * 42;   // wave-uniform address
#pragma unroll
            for (int c = 0; c < 42; ++c) acc[c] = fmaf(xs, Wr[c], acc[c]);
        }
    }

    // stage partial sums: conflict-free (lane-consecutive) writes
#pragma unroll
    for (int c = 0; c < 42; ++c) part[c * 256 + wave * 64 + lane] = acc[c];
    __syncthreads();

    // 448 channels per block, 2 per thread max
    for (int ch = tid; ch < 448; ch += 256) {
        const int r = ch / 7;
        const int d = ch - r * 7;

        float goal = bias[d];
#pragma unroll
        for (int w = 0; w < 4; ++w) goal += part[d * 256 + w * 64 + r];

        float wv[5];
#pragma unroll
        for (int i = 0; i < 5; ++i) {
            const int c = 7 + 5 * d + i;
            float s = bias[c];
#pragma unroll
            for (int w = 0; w < 4; ++w) s += part[c * 256 + w * 64 + r];
            wv[i] = s;
        }

        const float y0 = state[(size_t)blk * 448 + ch];
        const float gp = goal - y0;
        float* ob = out + (size_t)blk * 4928 + (size_t)r * 77 + d;

#pragma unroll
        for (int tt = 0; tt < 11; ++tt) {
            const float a  = tbl[tt * 8 + 0];
            const float cg = tbl[tt * 8 + 1];
            const float dc = tbl[tt * 8 + 2];
            float p = tbl[tt * 8 + 3] * wv[0];
            p = fmaf(tbl[tt * 8 + 4], wv[1], p);
            p = fmaf(tbl[tt * 8 + 5], wv[2], p);
            p = fmaf(tbl[tt * 8 + 6], wv[3], p);
            p = fmaf(tbl[tt * 8 + 7], wv[4], p);
            float y = fmaf(a, y0, dc);
            y = fmaf(cg, goal, y);
            y = fmaf(gp, p, y);
            ob[tt * 7] = y;
        }
    }
}

extern "C" void kernel_launch(void* const* d_in, const int* in_sizes, int n_in,
                              void* d_out, int out_size, void* d_ws, size_t ws_size,
                              hipStream_t stream) {
    const float* x     = (const float*)d_in[0];  // [65536,256]
    const float* state = (const float*)d_in[1];  // [65536,7]
    const float* W     = (const float*)d_in[2];  // [256,42]
    const float* b     = (const float*)d_in[3];  // [42]
    float* tbl = (float*)d_ws;                   // 88 floats
    float* out = (float*)d_out;

    dmp_setup_kernel<<<1, 128, 0, stream>>>(tbl);
    dmp_main_kernel<<<1024, 256, 0, stream>>>(x, state, W, b, tbl, out);
}